// Round 2
// baseline (669.931 us; speedup 1.0000x reference)
//
#include <hip/hip_runtime.h>

typedef __bf16 bf16x8 __attribute__((ext_vector_type(8)));
typedef float f32x4 __attribute__((ext_vector_type(4)));
typedef unsigned short u16x8 __attribute__((ext_vector_type(8)));
typedef unsigned short u16x4 __attribute__((ext_vector_type(4)));
typedef unsigned int __attribute__((address_space(1))) as1_uint;
typedef unsigned int __attribute__((address_space(3))) as3_uint;

#define S_LEN 2048
#define NB 4
#define NH 16
#define HD 64
#define DM 1024

// 0.125 (1/sqrt(64)) * log2(e): Q is pre-scaled so attn does exp2 directly.
#define Q_SCALE 0.18033688011112042f

__device__ __forceinline__ unsigned short f2bf(float f) {
  union { float f; unsigned int u; } v; v.f = f;
  unsigned int r = v.u + 0x7fffu + ((v.u >> 16) & 1u);
  return (unsigned short)(r >> 16);
}

// ---------- kernel 1: X fp32 -> bf16 (layout preserved, 8192x1024) ----------
__global__ __launch_bounds__(256) void cvt_x(const float* __restrict__ x,
                                             unsigned short* __restrict__ xb) {
  int i = (blockIdx.x * 256 + threadIdx.x) * 8;
  f32x4 a = *(const f32x4*)(x + i);
  f32x4 b = *(const f32x4*)(x + i + 4);
  u16x8 o;
  o[0] = f2bf(a[0]); o[1] = f2bf(a[1]); o[2] = f2bf(a[2]); o[3] = f2bf(a[3]);
  o[4] = f2bf(b[0]); o[5] = f2bf(b[1]); o[6] = f2bf(b[2]); o[7] = f2bf(b[3]);
  *(u16x8*)(xb + i) = o;
}

// ---------- kernel 2: W (K,N) fp32 -> WT (N,K) bf16, for q/k/v via blockIdx.z ----------
__global__ __launch_bounds__(256) void cvt_wt(const float* __restrict__ Wq,
                                              const float* __restrict__ Wk,
                                              const float* __restrict__ Wv,
                                              unsigned short* __restrict__ wt) {
  const float* W = (blockIdx.z == 0) ? Wq : (blockIdx.z == 1) ? Wk : Wv;
  unsigned short* WT = wt + (size_t)blockIdx.z * DM * DM;
  __shared__ float tile[32][33];
  int tx = threadIdx.x & 31, ty = threadIdx.x >> 5;
  int k0 = blockIdx.x * 32, n0 = blockIdx.y * 32;
#pragma unroll
  for (int i = 0; i < 4; ++i)
    tile[ty + 8 * i][tx] = W[(size_t)(k0 + ty + 8 * i) * DM + n0 + tx];
  __syncthreads();
#pragma unroll
  for (int i = 0; i < 4; ++i)
    WT[(size_t)(n0 + ty + 8 * i) * DM + k0 + tx] = f2bf(tile[tx][ty + 8 * i]);
}

// ---------- kernel 3: QKV GEMM: Y = Xb @ W + b ----------
// z=0 -> Q*Q_SCALE (B,H,S,HD) bf16 ; z=1 -> K (B,H,S,HD) bf16 ; z=2 -> V^T (B,H,HD,S) bf16
__global__ __launch_bounds__(256) void qkv_gemm(const unsigned short* __restrict__ xb,
                                                const unsigned short* __restrict__ wt,
                                                const float* __restrict__ bq,
                                                const float* __restrict__ bk,
                                                const float* __restrict__ bv,
                                                unsigned short* __restrict__ qo,
                                                unsigned short* __restrict__ ko,
                                                unsigned short* __restrict__ vto) {
  const int z = blockIdx.z;
  const unsigned short* WT = wt + (size_t)z * DM * DM;
  const float* bias = (z == 0) ? bq : (z == 1) ? bk : bv;
  const int m0 = blockIdx.x * 128;
  const int n0 = blockIdx.y * 128;
  __shared__ __align__(16) unsigned short Al[128 * 32];
  __shared__ __align__(16) unsigned short Bl[128 * 32];
  const int tid = threadIdx.x;
  const int wave = tid >> 6, lane = tid & 63, quad = lane >> 4, lw = lane & 15;
  const int wm = (wave >> 1) * 64, wn = (wave & 1) * 64;

  f32x4 acc[4][4];
#pragma unroll
  for (int mt = 0; mt < 4; ++mt)
#pragma unroll
    for (int nt = 0; nt < 4; ++nt) acc[mt][nt] = (f32x4){0.f, 0.f, 0.f, 0.f};

  for (int k0 = 0; k0 < DM; k0 += 32) {
    __syncthreads();
#pragma unroll
    for (int i = 0; i < 2; ++i) {
      int c = i * 256 + tid;
      const unsigned short* ga = xb + (size_t)(m0 + (c >> 2)) * DM + k0 + (c & 3) * 8;
      __builtin_amdgcn_global_load_lds((const as1_uint*)ga, (as3_uint*)(Al + c * 8), 16, 0, 0);
      const unsigned short* gb = WT + (size_t)(n0 + (c >> 2)) * DM + k0 + (c & 3) * 8;
      __builtin_amdgcn_global_load_lds((const as1_uint*)gb, (as3_uint*)(Bl + c * 8), 16, 0, 0);
    }
    __syncthreads();
    bf16x8 af[4], bfr[4];
#pragma unroll
    for (int mt = 0; mt < 4; ++mt)
      af[mt] = *(const bf16x8*)(Al + (wm + mt * 16 + lw) * 32 + quad * 8);
#pragma unroll
    for (int nt = 0; nt < 4; ++nt)
      bfr[nt] = *(const bf16x8*)(Bl + (wn + nt * 16 + lw) * 32 + quad * 8);
#pragma unroll
    for (int mt = 0; mt < 4; ++mt)
#pragma unroll
      for (int nt = 0; nt < 4; ++nt)
        acc[mt][nt] = __builtin_amdgcn_mfma_f32_16x16x32_bf16(af[mt], bfr[nt], acc[mt][nt], 0, 0, 0);
  }

  float bias4[4];
#pragma unroll
  for (int nt = 0; nt < 4; ++nt) bias4[nt] = bias[n0 + wn + nt * 16 + lw];

  if (z < 2) {
    unsigned short* dst = (z == 0) ? qo : ko;
    const float sc = (z == 0) ? Q_SCALE : 1.0f;
#pragma unroll
    for (int mt = 0; mt < 4; ++mt) {
#pragma unroll
      for (int nt = 0; nt < 4; ++nt) {
        int n = n0 + wn + nt * 16 + lw;
        int h = n >> 6, d = n & 63;
#pragma unroll
        for (int r = 0; r < 4; ++r) {
          int m = m0 + wm + mt * 16 + quad * 4 + r;
          int b = m >> 11, s = m & 2047;
          dst[((size_t)(b * NH + h) * S_LEN + s) * HD + d] = f2bf((acc[mt][nt][r] + bias4[nt]) * sc);
        }
      }
    }
  } else {
#pragma unroll
    for (int mt = 0; mt < 4; ++mt) {
#pragma unroll
      for (int nt = 0; nt < 4; ++nt) {
        int n = n0 + wn + nt * 16 + lw;
        int h = n >> 6, d = n & 63;
        int mb = m0 + wm + mt * 16 + quad * 4;
        int b = mb >> 11, s = mb & 2047;
        u16x4 pk;
#pragma unroll
        for (int r = 0; r < 4; ++r) pk[r] = f2bf(acc[mt][nt][r] + bias4[nt]);
        *(u16x4*)(vto + ((size_t)(b * NH + h) * HD + d) * S_LEN + s) = pk;
      }
    }
  }
}

// ---------- kernel 4: causal flash attention, no-max online softmax ----------
// Q pre-scaled by 0.125*log2(e) so P = exp2(QK^T). Denominator l computed via
// ones-vector MFMA (l = P @ 1) — no cross-lane shuffles anywhere in the loop.
// grid: (S/64, B*H), block 256 (4 waves, 16 q-rows each); KV tile = 128.
__global__ __launch_bounds__(256) void attn(const unsigned short* __restrict__ Qb,
                                            const unsigned short* __restrict__ Kb,
                                            const unsigned short* __restrict__ Vtb,
                                            float* __restrict__ out) {
  const int bh = blockIdx.y;
  const int b = bh >> 4, h = bh & 15;
  const int wave = threadIdx.x >> 6, lane = threadIdx.x & 63;
  const int quad = lane >> 4, lw = lane & 15;
  const int qblk = gridDim.x - 1 - blockIdx.x;  // long blocks dispatch first
  const int qw = qblk * 64 + wave * 16;
  const unsigned short* Qp = Qb + (size_t)bh * S_LEN * HD;
  const unsigned short* Kp = Kb + (size_t)bh * S_LEN * HD;
  const unsigned short* Vp = Vtb + (size_t)bh * HD * S_LEN;

  // P transpose buffer, per-wave private. Stride 132 shorts => b16 writes are
  // exactly 2-way bank aliased (free on gfx950).
  __shared__ __align__(16) unsigned short P_lds[4][16][132];
  unsigned short(*myP)[132] = P_lds[wave];

  bf16x8 aq0 = *(const bf16x8*)(Qp + (size_t)(qw + lw) * HD + quad * 8);
  bf16x8 aq1 = *(const bf16x8*)(Qp + (size_t)(qw + lw) * HD + 32 + quad * 8);

  u16x8 ones_u;
#pragma unroll
  for (int i = 0; i < 8; ++i) ones_u[i] = 0x3F80;  // bf16 1.0
  const bf16x8 onesf = __builtin_bit_cast(bf16x8, ones_u);

  f32x4 accO[4];
#pragma unroll
  for (int dg = 0; dg < 4; ++dg) accO[dg] = (f32x4){0.f, 0.f, 0.f, 0.f};
  f32x4 accL = (f32x4){0.f, 0.f, 0.f, 0.f};

  const int nk = qw + 16;  // keys visible to this wave's q rows
  const int ntiles = (nk + 127) >> 7;
  for (int t = 0; t < ntiles; ++t) {
    const int kv = t << 7;
    // --- QK^T over 128 keys (log2 domain, Q pre-scaled) ---
    f32x4 sc[8];
#pragma unroll
    for (int g = 0; g < 8; ++g) sc[g] = (f32x4){0.f, 0.f, 0.f, 0.f};
#pragma unroll
    for (int g = 0; g < 8; ++g) {
      const unsigned short* kr = Kp + (size_t)(kv + g * 16 + lw) * HD + quad * 8;
      sc[g] = __builtin_amdgcn_mfma_f32_16x16x32_bf16(aq0, *(const bf16x8*)kr, sc[g], 0, 0, 0);
      sc[g] = __builtin_amdgcn_mfma_f32_16x16x32_bf16(aq1, *(const bf16x8*)(kr + 32), sc[g], 0, 0, 0);
    }
    // --- P = exp2(sc), causal zeroing on diagonal tiles ---
    if (kv + 127 > qw) {
#pragma unroll
      for (int g = 0; g < 8; ++g)
#pragma unroll
        for (int r = 0; r < 4; ++r) {
          float e = __builtin_amdgcn_exp2f(sc[g][r]);
          sc[g][r] = (kv + g * 16 + lw > qw + quad * 4 + r) ? 0.f : e;
        }
    } else {
#pragma unroll
      for (int g = 0; g < 8; ++g)
#pragma unroll
        for (int r = 0; r < 4; ++r) sc[g][r] = __builtin_amdgcn_exp2f(sc[g][r]);
    }
    // --- C-layout -> A-layout via wave-private LDS ---
#pragma unroll
    for (int g = 0; g < 8; ++g)
#pragma unroll
      for (int r = 0; r < 4; ++r) myP[quad * 4 + r][g * 16 + lw] = f2bf(sc[g][r]);
    // --- V fragments (independent of LDS; overlap the lgkmcnt wait) ---
    bf16x8 vf[4][4];
#pragma unroll
    for (int dg = 0; dg < 4; ++dg)
#pragma unroll
      for (int j = 0; j < 4; ++j)
        vf[dg][j] = *(const bf16x8*)(Vp + (size_t)(dg * 16 + lw) * S_LEN + kv + j * 32 + quad * 8);
    bf16x8 ap[4];
#pragma unroll
    for (int j = 0; j < 4; ++j) ap[j] = *(const bf16x8*)&myP[lw][j * 32 + quad * 8];
    // --- O += P V ; l += P 1 ---
#pragma unroll
    for (int dg = 0; dg < 4; ++dg)
#pragma unroll
      for (int j = 0; j < 4; ++j)
        accO[dg] = __builtin_amdgcn_mfma_f32_16x16x32_bf16(ap[j], vf[dg][j], accO[dg], 0, 0, 0);
#pragma unroll
    for (int j = 0; j < 4; ++j)
      accL = __builtin_amdgcn_mfma_f32_16x16x32_bf16(ap[j], onesf, accL, 0, 0, 0);
  }

  float* op = out + ((size_t)b * S_LEN + qw + quad * 4) * DM + h * HD + lw;
#pragma unroll
  for (int r = 0; r < 4; ++r) {
    float inv = 1.0f / accL[r];
#pragma unroll
    for (int dg = 0; dg < 4; ++dg) op[(size_t)r * DM + dg * 16] = accO[dg][r] * inv;
  }
}

extern "C" void kernel_launch(void* const* d_in, const int* in_sizes, int n_in,
                              void* d_out, int out_size, void* d_ws, size_t ws_size,
                              hipStream_t stream) {
  const float* x = (const float*)d_in[0];
  const float* Wq = (const float*)d_in[1];
  const float* bq = (const float*)d_in[2];
  const float* Wk = (const float*)d_in[3];
  const float* bk = (const float*)d_in[4];
  const float* Wv = (const float*)d_in[5];
  const float* bv = (const float*)d_in[6];
  float* out = (float*)d_out;

  char* ws = (char*)d_ws;
  unsigned short* xb = (unsigned short*)(ws + 0);          // 16 MB: X bf16 (8192,1024)
  unsigned short* wt = (unsigned short*)(ws + 16777216);   // 6 MB: Wq/Wk/Wv^T bf16
  unsigned short* qb = (unsigned short*)(ws + 23068672);   // 16 MB: Q*scale (B,H,S,64)
  unsigned short* kb = (unsigned short*)(ws + 39845888);   // 16 MB: K (B,H,S,64)
  unsigned short* vt = (unsigned short*)(ws + 56623104);   // 16 MB: V^T (B,H,64,S)

  hipLaunchKernelGGL(cvt_x, dim3(4096), dim3(256), 0, stream, x, xb);
  hipLaunchKernelGGL(cvt_wt, dim3(32, 32, 3), dim3(256), 0, stream, Wq, Wk, Wv, wt);
  hipLaunchKernelGGL(qkv_gemm, dim3(64, 8, 3), dim3(256), 0, stream,
                     xb, wt, bq, bk, bv, qb, kb, vt);
  hipLaunchKernelGGL(attn, dim3(32, 64), dim3(256), 0, stream, qb, kb, vt, out);
}

// Round 3
// 311.747 us; speedup vs baseline: 2.1490x; 2.1490x over previous
//
#include <hip/hip_runtime.h>

typedef __bf16 bf16x8 __attribute__((ext_vector_type(8)));
typedef float f32x4 __attribute__((ext_vector_type(4)));
typedef unsigned short u16x8 __attribute__((ext_vector_type(8)));
typedef unsigned short u16x4 __attribute__((ext_vector_type(4)));
typedef unsigned int __attribute__((address_space(1))) as1_uint;
typedef unsigned int __attribute__((address_space(3))) as3_uint;

#define S_LEN 2048
#define NB 4
#define NH 16
#define HD 64
#define DM 1024

// 0.125 (1/sqrt(64)) * log2(e): Q is pre-scaled so attn does exp2 directly.
#define Q_SCALE 0.18033688011112042f

__device__ __forceinline__ unsigned short f2bf(float f) {
  union { float f; unsigned int u; } v; v.f = f;
  unsigned int r = v.u + 0x7fffu + ((v.u >> 16) & 1u);
  return (unsigned short)(r >> 16);
}

// ---------- kernel 1: X fp32 -> bf16 (layout preserved, 8192x1024) ----------
__global__ __launch_bounds__(256) void cvt_x(const float* __restrict__ x,
                                             unsigned short* __restrict__ xb) {
  int i = (blockIdx.x * 256 + threadIdx.x) * 8;
  f32x4 a = *(const f32x4*)(x + i);
  f32x4 b = *(const f32x4*)(x + i + 4);
  u16x8 o;
  o[0] = f2bf(a[0]); o[1] = f2bf(a[1]); o[2] = f2bf(a[2]); o[3] = f2bf(a[3]);
  o[4] = f2bf(b[0]); o[5] = f2bf(b[1]); o[6] = f2bf(b[2]); o[7] = f2bf(b[3]);
  *(u16x8*)(xb + i) = o;
}

// ---------- kernel 2: W (K,N) fp32 -> WT (N,K) bf16, for q/k/v via blockIdx.z ----------
__global__ __launch_bounds__(256) void cvt_wt(const float* __restrict__ Wq,
                                              const float* __restrict__ Wk,
                                              const float* __restrict__ Wv,
                                              unsigned short* __restrict__ wt) {
  const float* W = (blockIdx.z == 0) ? Wq : (blockIdx.z == 1) ? Wk : Wv;
  unsigned short* WT = wt + (size_t)blockIdx.z * DM * DM;
  __shared__ float tile[32][33];
  int tx = threadIdx.x & 31, ty = threadIdx.x >> 5;
  int k0 = blockIdx.x * 32, n0 = blockIdx.y * 32;
#pragma unroll
  for (int i = 0; i < 4; ++i)
    tile[ty + 8 * i][tx] = W[(size_t)(k0 + ty + 8 * i) * DM + n0 + tx];
  __syncthreads();
#pragma unroll
  for (int i = 0; i < 4; ++i)
    WT[(size_t)(n0 + ty + 8 * i) * DM + k0 + tx] = f2bf(tile[tx][ty + 8 * i]);
}

// ---------- kernel 3: QKV GEMM: Y = Xb @ W + b ----------
// z=0 -> Q*Q_SCALE (B,H,S,HD) bf16 ; z=1 -> K (B,H,S,HD) bf16 ; z=2 -> V^T (B,H,HD,S) bf16
__global__ __launch_bounds__(256) void qkv_gemm(const unsigned short* __restrict__ xb,
                                                const unsigned short* __restrict__ wt,
                                                const float* __restrict__ bq,
                                                const float* __restrict__ bk,
                                                const float* __restrict__ bv,
                                                unsigned short* __restrict__ qo,
                                                unsigned short* __restrict__ ko,
                                                unsigned short* __restrict__ vto) {
  const int z = blockIdx.z;
  const unsigned short* WT = wt + (size_t)z * DM * DM;
  const float* bias = (z == 0) ? bq : (z == 1) ? bk : bv;
  const int m0 = blockIdx.x * 128;
  const int n0 = blockIdx.y * 128;
  __shared__ __align__(16) unsigned short Al[128 * 32];
  __shared__ __align__(16) unsigned short Bl[128 * 32];
  const int tid = threadIdx.x;
  const int wave = tid >> 6, lane = tid & 63, quad = lane >> 4, lw = lane & 15;
  const int wm = (wave >> 1) * 64, wn = (wave & 1) * 64;

  f32x4 acc[4][4];
#pragma unroll
  for (int mt = 0; mt < 4; ++mt)
#pragma unroll
    for (int nt = 0; nt < 4; ++nt) acc[mt][nt] = (f32x4){0.f, 0.f, 0.f, 0.f};

  for (int k0 = 0; k0 < DM; k0 += 32) {
    __syncthreads();
#pragma unroll
    for (int i = 0; i < 2; ++i) {
      int c = i * 256 + tid;
      const unsigned short* ga = xb + (size_t)(m0 + (c >> 2)) * DM + k0 + (c & 3) * 8;
      __builtin_amdgcn_global_load_lds((const as1_uint*)ga, (as3_uint*)(Al + c * 8), 16, 0, 0);
      const unsigned short* gb = WT + (size_t)(n0 + (c >> 2)) * DM + k0 + (c & 3) * 8;
      __builtin_amdgcn_global_load_lds((const as1_uint*)gb, (as3_uint*)(Bl + c * 8), 16, 0, 0);
    }
    __syncthreads();
    bf16x8 af[4], bfr[4];
#pragma unroll
    for (int mt = 0; mt < 4; ++mt)
      af[mt] = *(const bf16x8*)(Al + (wm + mt * 16 + lw) * 32 + quad * 8);
#pragma unroll
    for (int nt = 0; nt < 4; ++nt)
      bfr[nt] = *(const bf16x8*)(Bl + (wn + nt * 16 + lw) * 32 + quad * 8);
#pragma unroll
    for (int mt = 0; mt < 4; ++mt)
#pragma unroll
      for (int nt = 0; nt < 4; ++nt)
        acc[mt][nt] = __builtin_amdgcn_mfma_f32_16x16x32_bf16(af[mt], bfr[nt], acc[mt][nt], 0, 0, 0);
  }

  float bias4[4];
#pragma unroll
  for (int nt = 0; nt < 4; ++nt) bias4[nt] = bias[n0 + wn + nt * 16 + lw];

  if (z < 2) {
    unsigned short* dst = (z == 0) ? qo : ko;
    const float sc = (z == 0) ? Q_SCALE : 1.0f;
#pragma unroll
    for (int mt = 0; mt < 4; ++mt) {
#pragma unroll
      for (int nt = 0; nt < 4; ++nt) {
        int n = n0 + wn + nt * 16 + lw;
        int h = n >> 6, d = n & 63;
#pragma unroll
        for (int r = 0; r < 4; ++r) {
          int m = m0 + wm + mt * 16 + quad * 4 + r;
          int b = m >> 11, s = m & 2047;
          dst[((size_t)(b * NH + h) * S_LEN + s) * HD + d] = f2bf((acc[mt][nt][r] + bias4[nt]) * sc);
        }
      }
    }
  } else {
#pragma unroll
    for (int mt = 0; mt < 4; ++mt) {
#pragma unroll
      for (int nt = 0; nt < 4; ++nt) {
        int n = n0 + wn + nt * 16 + lw;
        int h = n >> 6, d = n & 63;
        int mb = m0 + wm + mt * 16 + quad * 4;
        int b = mb >> 11, s = mb & 2047;
        u16x4 pk;
#pragma unroll
        for (int r = 0; r < 4; ++r) pk[r] = f2bf(acc[mt][nt][r] + bias4[nt]);
        *(u16x4*)(vto + ((size_t)(b * NH + h) * HD + d) * S_LEN + s) = pk;
      }
    }
  }
}

// ---------- kernel 4: causal flash attention, block-cooperative LDS staging ----
// Block covers 128 q rows; wave w owns rows {base+w*16+lw} (rg0) and
// {base+64+w*16+lw} (rg1). K (64x64) and V^T (64x64) tiles staged to LDS via
// global_load_lds with an XOR chunk swizzle folded into the GLOBAL address
// (LDS side must stay lane-contiguous). No-max softmax: P = exp2(QK), l = P@1.
// grid: (S/128, B*H), block 256.
__global__ __launch_bounds__(256, 4) void attn(const unsigned short* __restrict__ Qb,
                                               const unsigned short* __restrict__ Kb,
                                               const unsigned short* __restrict__ Vtb,
                                               float* __restrict__ out) {
  const int bh = blockIdx.y;
  const int b = bh >> 4, h = bh & 15;
  const int tid = threadIdx.x;
  const int wave = tid >> 6, lane = tid & 63;
  const int quad = lane >> 4, lw = lane & 15;
  const int qblk = gridDim.x - 1 - blockIdx.x;  // heavy blocks dispatch first
  const int base = qblk * 128;
  const unsigned short* Qp = Qb + (size_t)bh * S_LEN * HD;
  const unsigned short* Kp = Kb + (size_t)bh * S_LEN * HD;
  const unsigned short* Vp = Vtb + (size_t)bh * HD * S_LEN;

  __shared__ __align__(16) unsigned short Kl[64 * 64];
  __shared__ __align__(16) unsigned short Vl[64 * 64];
  __shared__ __align__(16) unsigned short Pl[4][16][132];
  unsigned short(*myP)[132] = Pl[wave];

  bf16x8 aq[2][2];
#pragma unroll
  for (int rg = 0; rg < 2; ++rg)
#pragma unroll
    for (int kc = 0; kc < 2; ++kc)
      aq[rg][kc] = *(const bf16x8*)(Qp + (size_t)(base + rg * 64 + wave * 16 + lw) * HD + kc * 32 + quad * 8);

  u16x8 ones_u;
#pragma unroll
  for (int i = 0; i < 8; ++i) ones_u[i] = 0x3F80;  // bf16 1.0
  const bf16x8 onesf = __builtin_bit_cast(bf16x8, ones_u);

  f32x4 accO[2][4];
  f32x4 accL[2];
#pragma unroll
  for (int rg = 0; rg < 2; ++rg) {
    accL[rg] = (f32x4){0.f, 0.f, 0.f, 0.f};
#pragma unroll
    for (int dg = 0; dg < 4; ++dg) accO[rg][dg] = (f32x4){0.f, 0.f, 0.f, 0.f};
  }

  const int T = 2 * (qblk + 1);
  for (int t = 0; t < T; ++t) {
    const int kv = t * 64;
    __syncthreads();  // previous tile's LDS reads done
#pragma unroll
    for (int i = 0; i < 2; ++i) {
      int idx = i * 256 + tid;
      int r = idx >> 3, c = (idx & 7) ^ (r & 7);  // xor-swizzled source chunk
      __builtin_amdgcn_global_load_lds((const as1_uint*)(Kp + (size_t)(kv + r) * HD + c * 8),
                                       (as3_uint*)(Kl + idx * 8), 16, 0, 0);
      __builtin_amdgcn_global_load_lds((const as1_uint*)(Vp + (size_t)r * S_LEN + kv + c * 8),
                                       (as3_uint*)(Vl + idx * 8), 16, 0, 0);
    }
    __syncthreads();  // staging visible

    const bool act0 = (kv <= base + wave * 16 + 15);  // rg1 is active on every tile
    bf16x8 ap[2][2];
#pragma unroll
    for (int rg = 0; rg < 2; ++rg) {
      if (rg == 0 && !act0) continue;
      const int qrow0 = base + rg * 64 + wave * 16;
      f32x4 sc[4];
#pragma unroll
      for (int g = 0; g < 4; ++g) sc[g] = (f32x4){0.f, 0.f, 0.f, 0.f};
#pragma unroll
      for (int g = 0; g < 4; ++g) {
        const int n = g * 16 + lw;
        const unsigned short* krow = Kl + n * 64;
        const int sw = n & 7;
        bf16x8 kf0 = *(const bf16x8*)(krow + ((quad ^ sw) * 8));
        bf16x8 kf1 = *(const bf16x8*)(krow + (((4 + quad) ^ sw) * 8));
        sc[g] = __builtin_amdgcn_mfma_f32_16x16x32_bf16(aq[rg][0], kf0, sc[g], 0, 0, 0);
        sc[g] = __builtin_amdgcn_mfma_f32_16x16x32_bf16(aq[rg][1], kf1, sc[g], 0, 0, 0);
      }
      if (kv + 63 > qrow0) {
#pragma unroll
        for (int g = 0; g < 4; ++g)
#pragma unroll
          for (int r = 0; r < 4; ++r) {
            float e = __builtin_amdgcn_exp2f(sc[g][r]);
            sc[g][r] = (kv + g * 16 + lw > qrow0 + quad * 4 + r) ? 0.f : e;
          }
      } else {
#pragma unroll
        for (int g = 0; g < 4; ++g)
#pragma unroll
          for (int r = 0; r < 4; ++r) sc[g][r] = __builtin_amdgcn_exp2f(sc[g][r]);
      }
#pragma unroll
      for (int g = 0; g < 4; ++g)
#pragma unroll
        for (int r = 0; r < 4; ++r) myP[quad * 4 + r][g * 16 + lw] = f2bf(sc[g][r]);
      ap[rg][0] = *(const bf16x8*)&myP[lw][quad * 8];
      ap[rg][1] = *(const bf16x8*)&myP[lw][32 + quad * 8];
    }

#pragma unroll
    for (int j2 = 0; j2 < 2; ++j2) {
      bf16x8 vf[4];
#pragma unroll
      for (int dg = 0; dg < 4; ++dg) {
        const int d = dg * 16 + lw;
        vf[dg] = *(const bf16x8*)(Vl + d * 64 + (((4 * j2 + quad) ^ (d & 7)) * 8));
      }
      if (act0) {
#pragma unroll
        for (int dg = 0; dg < 4; ++dg)
          accO[0][dg] = __builtin_amdgcn_mfma_f32_16x16x32_bf16(ap[0][j2], vf[dg], accO[0][dg], 0, 0, 0);
        accL[0] = __builtin_amdgcn_mfma_f32_16x16x32_bf16(ap[0][j2], onesf, accL[0], 0, 0, 0);
      }
#pragma unroll
      for (int dg = 0; dg < 4; ++dg)
        accO[1][dg] = __builtin_amdgcn_mfma_f32_16x16x32_bf16(ap[1][j2], vf[dg], accO[1][dg], 0, 0, 0);
      accL[1] = __builtin_amdgcn_mfma_f32_16x16x32_bf16(ap[1][j2], onesf, accL[1], 0, 0, 0);
    }
  }

#pragma unroll
  for (int rg = 0; rg < 2; ++rg) {
    float* op = out + ((size_t)b * S_LEN + base + rg * 64 + wave * 16 + quad * 4) * DM + h * HD + lw;
#pragma unroll
    for (int r = 0; r < 4; ++r) {
      float inv = 1.0f / accL[rg][r];
#pragma unroll
      for (int dg = 0; dg < 4; ++dg) op[(size_t)r * DM + dg * 16] = accO[rg][dg][r] * inv;
    }
  }
}

extern "C" void kernel_launch(void* const* d_in, const int* in_sizes, int n_in,
                              void* d_out, int out_size, void* d_ws, size_t ws_size,
                              hipStream_t stream) {
  const float* x = (const float*)d_in[0];
  const float* Wq = (const float*)d_in[1];
  const float* bq = (const float*)d_in[2];
  const float* Wk = (const float*)d_in[3];
  const float* bk = (const float*)d_in[4];
  const float* Wv = (const float*)d_in[5];
  const float* bv = (const float*)d_in[6];
  float* out = (float*)d_out;

  char* ws = (char*)d_ws;
  unsigned short* xb = (unsigned short*)(ws + 0);          // 16 MB: X bf16 (8192,1024)
  unsigned short* wt = (unsigned short*)(ws + 16777216);   // 6 MB: Wq/Wk/Wv^T bf16
  unsigned short* qb = (unsigned short*)(ws + 23068672);   // 16 MB: Q*scale (B,H,S,64)
  unsigned short* kb = (unsigned short*)(ws + 39845888);   // 16 MB: K (B,H,S,64)
  unsigned short* vt = (unsigned short*)(ws + 56623104);   // 16 MB: V^T (B,H,64,S)

  hipLaunchKernelGGL(cvt_x, dim3(4096), dim3(256), 0, stream, x, xb);
  hipLaunchKernelGGL(cvt_wt, dim3(32, 32, 3), dim3(256), 0, stream, Wq, Wk, Wv, wt);
  hipLaunchKernelGGL(qkv_gemm, dim3(64, 8, 3), dim3(256), 0, stream,
                     xb, wt, bq, bk, bv, qb, kb, vt);
  hipLaunchKernelGGL(attn, dim3(16, 64), dim3(256), 0, stream, qb, kb, vt, out);
}

// Round 4
// 227.936 us; speedup vs baseline: 2.9391x; 1.3677x over previous
//
#include <hip/hip_runtime.h>

typedef __bf16 bf16x8 __attribute__((ext_vector_type(8)));
typedef __bf16 bf16x4 __attribute__((ext_vector_type(4)));
typedef short s16x4 __attribute__((ext_vector_type(4)));
typedef float f32x4 __attribute__((ext_vector_type(4)));
typedef unsigned short u16x8 __attribute__((ext_vector_type(8)));
typedef unsigned short u16x4 __attribute__((ext_vector_type(4)));
typedef unsigned int u32x2 __attribute__((ext_vector_type(2)));
typedef unsigned int __attribute__((address_space(1))) as1_uint;
typedef unsigned int __attribute__((address_space(3))) as3_uint;

#define S_LEN 2048
#define NB 4
#define NH 16
#define HD 64
#define DM 1024

// 0.125 (1/sqrt(64)) * log2(e): Q is pre-scaled so attn does exp2 directly.
#define Q_SCALE 0.18033688011112042f

__device__ __forceinline__ unsigned short f2bf(float f) {
  union { float f; unsigned int u; } v; v.f = f;
  unsigned int r = v.u + 0x7fffu + ((v.u >> 16) & 1u);
  return (unsigned short)(r >> 16);
}

__device__ __forceinline__ unsigned int fbits(float f) {
  union { float f; unsigned int u; } v; v.f = f;
  return v.u;
}

// 16x16x16 bf16 MFMA with builtin-name portability.
__device__ __forceinline__ f32x4 mfma16(u16x4 a, u16x4 b, f32x4 c) {
#if __has_builtin(__builtin_amdgcn_mfma_f32_16x16x16_bf16)
  return __builtin_amdgcn_mfma_f32_16x16x16_bf16(
      __builtin_bit_cast(bf16x4, a), __builtin_bit_cast(bf16x4, b), c, 0, 0, 0);
#else
  return __builtin_amdgcn_mfma_f32_16x16x16bf16_1k(
      __builtin_bit_cast(s16x4, a), __builtin_bit_cast(s16x4, b), c, 0, 0, 0);
#endif
}

// ---------- kernel 1: X fp32 -> bf16 (layout preserved, 8192x1024) ----------
__global__ __launch_bounds__(256) void cvt_x(const float* __restrict__ x,
                                             unsigned short* __restrict__ xb) {
  int i = (blockIdx.x * 256 + threadIdx.x) * 8;
  f32x4 a = *(const f32x4*)(x + i);
  f32x4 b = *(const f32x4*)(x + i + 4);
  u16x8 o;
  o[0] = f2bf(a[0]); o[1] = f2bf(a[1]); o[2] = f2bf(a[2]); o[3] = f2bf(a[3]);
  o[4] = f2bf(b[0]); o[5] = f2bf(b[1]); o[6] = f2bf(b[2]); o[7] = f2bf(b[3]);
  *(u16x8*)(xb + i) = o;
}

// ---------- kernel 2: W (K,N) fp32 -> WT (N,K) bf16, for q/k/v via blockIdx.z ----------
__global__ __launch_bounds__(256) void cvt_wt(const float* __restrict__ Wq,
                                              const float* __restrict__ Wk,
                                              const float* __restrict__ Wv,
                                              unsigned short* __restrict__ wt) {
  const float* W = (blockIdx.z == 0) ? Wq : (blockIdx.z == 1) ? Wk : Wv;
  unsigned short* WT = wt + (size_t)blockIdx.z * DM * DM;
  __shared__ float tile[32][33];
  int tx = threadIdx.x & 31, ty = threadIdx.x >> 5;
  int k0 = blockIdx.x * 32, n0 = blockIdx.y * 32;
#pragma unroll
  for (int i = 0; i < 4; ++i)
    tile[ty + 8 * i][tx] = W[(size_t)(k0 + ty + 8 * i) * DM + n0 + tx];
  __syncthreads();
#pragma unroll
  for (int i = 0; i < 4; ++i)
    WT[(size_t)(n0 + ty + 8 * i) * DM + k0 + tx] = f2bf(tile[tx][ty + 8 * i]);
}

// ---------- kernel 3: QKV GEMM: Y = Xb @ W + b ----------
// z=0 -> Q*Q_SCALE (B,H,S,HD) bf16 ; z=1 -> K (B,H,S,HD) bf16 ; z=2 -> V^T (B,H,HD,S) bf16
__global__ __launch_bounds__(256) void qkv_gemm(const unsigned short* __restrict__ xb,
                                                const unsigned short* __restrict__ wt,
                                                const float* __restrict__ bq,
                                                const float* __restrict__ bk,
                                                const float* __restrict__ bv,
                                                unsigned short* __restrict__ qo,
                                                unsigned short* __restrict__ ko,
                                                unsigned short* __restrict__ vto) {
  const int z = blockIdx.z;
  const unsigned short* WT = wt + (size_t)z * DM * DM;
  const float* bias = (z == 0) ? bq : (z == 1) ? bk : bv;
  const int m0 = blockIdx.x * 128;
  const int n0 = blockIdx.y * 128;
  __shared__ __align__(16) unsigned short Al[128 * 32];
  __shared__ __align__(16) unsigned short Bl[128 * 32];
  const int tid = threadIdx.x;
  const int wave = tid >> 6, lane = tid & 63, quad = lane >> 4, lw = lane & 15;
  const int wm = (wave >> 1) * 64, wn = (wave & 1) * 64;

  f32x4 acc[4][4];
#pragma unroll
  for (int mt = 0; mt < 4; ++mt)
#pragma unroll
    for (int nt = 0; nt < 4; ++nt) acc[mt][nt] = (f32x4){0.f, 0.f, 0.f, 0.f};

  for (int k0 = 0; k0 < DM; k0 += 32) {
    __syncthreads();
#pragma unroll
    for (int i = 0; i < 2; ++i) {
      int c = i * 256 + tid;
      const unsigned short* ga = xb + (size_t)(m0 + (c >> 2)) * DM + k0 + (c & 3) * 8;
      __builtin_amdgcn_global_load_lds((const as1_uint*)ga, (as3_uint*)(Al + c * 8), 16, 0, 0);
      const unsigned short* gb = WT + (size_t)(n0 + (c >> 2)) * DM + k0 + (c & 3) * 8;
      __builtin_amdgcn_global_load_lds((const as1_uint*)gb, (as3_uint*)(Bl + c * 8), 16, 0, 0);
    }
    __syncthreads();
    bf16x8 af[4], bfr[4];
#pragma unroll
    for (int mt = 0; mt < 4; ++mt)
      af[mt] = *(const bf16x8*)(Al + (wm + mt * 16 + lw) * 32 + quad * 8);
#pragma unroll
    for (int nt = 0; nt < 4; ++nt)
      bfr[nt] = *(const bf16x8*)(Bl + (wn + nt * 16 + lw) * 32 + quad * 8);
#pragma unroll
    for (int mt = 0; mt < 4; ++mt)
#pragma unroll
      for (int nt = 0; nt < 4; ++nt)
        acc[mt][nt] = __builtin_amdgcn_mfma_f32_16x16x32_bf16(af[mt], bfr[nt], acc[mt][nt], 0, 0, 0);
  }

  float bias4[4];
#pragma unroll
  for (int nt = 0; nt < 4; ++nt) bias4[nt] = bias[n0 + wn + nt * 16 + lw];

  if (z < 2) {
    unsigned short* dst = (z == 0) ? qo : ko;
    const float sc = (z == 0) ? Q_SCALE : 1.0f;
#pragma unroll
    for (int mt = 0; mt < 4; ++mt) {
#pragma unroll
      for (int nt = 0; nt < 4; ++nt) {
        int n = n0 + wn + nt * 16 + lw;
        int h = n >> 6, d = n & 63;
#pragma unroll
        for (int r = 0; r < 4; ++r) {
          int m = m0 + wm + mt * 16 + quad * 4 + r;
          int b = m >> 11, s = m & 2047;
          dst[((size_t)(b * NH + h) * S_LEN + s) * HD + d] = f2bf((acc[mt][nt][r] + bias4[nt]) * sc);
        }
      }
    }
  } else {
#pragma unroll
    for (int mt = 0; mt < 4; ++mt) {
#pragma unroll
      for (int nt = 0; nt < 4; ++nt) {
        int n = n0 + wn + nt * 16 + lw;
        int h = n >> 6, d = n & 63;
        int mb = m0 + wm + mt * 16 + quad * 4;
        int b = mb >> 11, s = mb & 2047;
        u16x4 pk;
#pragma unroll
        for (int r = 0; r < 4; ++r) pk[r] = f2bf(acc[mt][nt][r] + bias4[nt]);
        *(u16x4*)(vto + ((size_t)(b * NH + h) * HD + d) * S_LEN + s) = pk;
      }
    }
  }
}

// ---------- kernel 4: causal flash attention, register-resident P ------------
// S^T = K·Q^T via mfma 16x16x32 (A=K, B=Q). S^T's C-layout (key=quad*4+r,
// qrow=lane&15) IS the A-fragment layout of mfma 16x16x16, so P feeds PV
// directly from registers — no LDS transpose. l = P@1 via ones-MFMA.
// Complementary pairing: block pair i owns q rows [i*64) and [(31-i)*64):
// every block = exactly 33 row-group-tile units. Grid 1024 = fully resident.
// Flat block id swizzled so one (b,h)'s 16 blocks share an XCD (L2 reuse).
__global__ __launch_bounds__(256, 4) void attn(const unsigned short* __restrict__ Qb,
                                               const unsigned short* __restrict__ Kb,
                                               const unsigned short* __restrict__ Vtb,
                                               float* __restrict__ out) {
  const int flat = blockIdx.x;
  const int bh_lo = flat & 7;
  const int qpair = (flat >> 3) & 15;
  const int bh_hi = flat >> 7;
  const int bh = bh_lo + 8 * bh_hi;
  const int b = bh >> 4, h = bh & 15;
  const int tid = threadIdx.x;
  const int wave = tid >> 6, lane = tid & 63;
  const int quad = lane >> 4, lw = lane & 15;
  const int qlo = qpair * 64;         // row group 0
  const int qhi = (31 - qpair) * 64;  // row group 1
  const unsigned short* Qp = Qb + (size_t)bh * S_LEN * HD;
  const unsigned short* Kp = Kb + (size_t)bh * S_LEN * HD;
  const unsigned short* Vp = Vtb + (size_t)bh * HD * S_LEN;

  __shared__ __align__(16) unsigned short Kl[64 * 64];
  __shared__ __align__(16) unsigned short Vl[64 * 64];

  // Q fragments (B-operand: n=qrow=lane&15, k=quad*8+j)
  bf16x8 aq[2][2];
#pragma unroll
  for (int rg = 0; rg < 2; ++rg) {
    const int qbase = rg ? qhi : qlo;
#pragma unroll
    for (int kc = 0; kc < 2; ++kc)
      aq[rg][kc] = *(const bf16x8*)(Qp + (size_t)(qbase + wave * 16 + lw) * HD + kc * 32 + quad * 8);
  }

  u16x4 ones4;
#pragma unroll
  for (int i = 0; i < 4; ++i) ones4[i] = 0x3F80;

  f32x4 accO[2][4];
  f32x4 accL[2];
#pragma unroll
  for (int rg = 0; rg < 2; ++rg) {
    accL[rg] = (f32x4){0.f, 0.f, 0.f, 0.f};
#pragma unroll
    for (int dg = 0; dg < 4; ++dg) accO[rg][dg] = (f32x4){0.f, 0.f, 0.f, 0.f};
  }

  const int qr0 = qlo + wave * 16 + lw;  // this lane's q row, group 0
  const int qr1 = qhi + wave * 16 + lw;  // group 1

  const int T = 32 - qpair;  // tiles to cover qhi+63
  for (int t = 0; t < T; ++t) {
    const int kv = t * 64;
    __syncthreads();  // previous tile's LDS reads done
#pragma unroll
    for (int i = 0; i < 2; ++i) {
      int idx = i * 256 + tid;
      int r = idx >> 3, c = (idx & 7) ^ (r & 7);  // xor-swizzled source chunk
      __builtin_amdgcn_global_load_lds((const as1_uint*)(Kp + (size_t)(kv + r) * HD + c * 8),
                                       (as3_uint*)(Kl + idx * 8), 16, 0, 0);
      __builtin_amdgcn_global_load_lds((const as1_uint*)(Vp + (size_t)r * S_LEN + kv + c * 8),
                                       (as3_uint*)(Vl + idx * 8), 16, 0, 0);
    }
    __syncthreads();  // staging visible

    const bool a0 = (t <= qpair);   // rg0 active this tile (wave-uniform)
    const bool d0 = (t == qpair);   // rg0 diagonal tile
    const bool d1 = (t == T - 1);   // rg1 diagonal tile

#pragma unroll
    for (int g = 0; g < 4; ++g) {
      // K A-fragment: m = key = g*16+lw, k = quad*8+j (shared by both rg)
      const unsigned short* kp = Kl + (g * 16 + lw) * 64;
      const int sw = lw & 7;
      bf16x8 kf0 = *(const bf16x8*)(kp + ((quad ^ sw) * 8));
      bf16x8 kf1 = *(const bf16x8*)(kp + (((4 + quad) ^ sw) * 8));

      u16x4 pf[2];
#pragma unroll
      for (int rg = 0; rg < 2; ++rg) {
        if (rg == 0 && !a0) continue;
        f32x4 s = (f32x4){0.f, 0.f, 0.f, 0.f};
        s = __builtin_amdgcn_mfma_f32_16x16x32_bf16(kf0, aq[rg][0], s, 0, 0, 0);
        s = __builtin_amdgcn_mfma_f32_16x16x32_bf16(kf1, aq[rg][1], s, 0, 0, 0);
        const bool dg_ = rg ? d1 : d0;
        const int qr = rg ? qr1 : qr0;
        if (dg_) {
#pragma unroll
          for (int r = 0; r < 4; ++r) {
            float e = __builtin_amdgcn_exp2f(s[r]);
            s[r] = (kv + g * 16 + quad * 4 + r > qr) ? 0.f : e;
          }
        } else {
#pragma unroll
          for (int r = 0; r < 4; ++r) s[r] = __builtin_amdgcn_exp2f(s[r]);
        }
        // pack to bf16 (truncate; downward bias cancels in P/l)
        u32x2 pk;
        pk[0] = (fbits(s[1]) & 0xFFFF0000u) | (fbits(s[0]) >> 16);
        pk[1] = (fbits(s[3]) & 0xFFFF0000u) | (fbits(s[2]) >> 16);
        pf[rg] = __builtin_bit_cast(u16x4, pk);
      }

      // PV for this 16-key chunk: B = V^T fragment (b64), shared by both rg
#pragma unroll
      for (int dg = 0; dg < 4; ++dg) {
        const int row = dg * 16 + lw;
        const int slot = (2 * g + (quad >> 1)) ^ (lw & 7);
        u16x4 vf = *(const u16x4*)(Vl + row * 64 + slot * 8 + (quad & 1) * 4);
        if (a0) accO[0][dg] = mfma16(pf[0], vf, accO[0][dg]);
        accO[1][dg] = mfma16(pf[1], vf, accO[1][dg]);
      }
      if (a0) accL[0] = mfma16(pf[0], ones4, accL[0]);
      accL[1] = mfma16(pf[1], ones4, accL[1]);
    }
  }

#pragma unroll
  for (int rg = 0; rg < 2; ++rg) {
    const int qbase = rg ? qhi : qlo;
    float* op = out + ((size_t)b * S_LEN + qbase + wave * 16 + quad * 4) * DM + h * HD + lw;
#pragma unroll
    for (int r = 0; r < 4; ++r) {
      float inv = 1.0f / accL[rg][r];
#pragma unroll
      for (int dg = 0; dg < 4; ++dg) op[(size_t)r * DM + dg * 16] = accO[rg][dg][r] * inv;
    }
  }
}

extern "C" void kernel_launch(void* const* d_in, const int* in_sizes, int n_in,
                              void* d_out, int out_size, void* d_ws, size_t ws_size,
                              hipStream_t stream) {
  const float* x = (const float*)d_in[0];
  const float* Wq = (const float*)d_in[1];
  const float* bq = (const float*)d_in[2];
  const float* Wk = (const float*)d_in[3];
  const float* bk = (const float*)d_in[4];
  const float* Wv = (const float*)d_in[5];
  const float* bv = (const float*)d_in[6];
  float* out = (float*)d_out;

  char* ws = (char*)d_ws;
  unsigned short* xb = (unsigned short*)(ws + 0);          // 16 MB: X bf16 (8192,1024)
  unsigned short* wt = (unsigned short*)(ws + 16777216);   // 6 MB: Wq/Wk/Wv^T bf16
  unsigned short* qb = (unsigned short*)(ws + 23068672);   // 16 MB: Q*scale (B,H,S,64)
  unsigned short* kb = (unsigned short*)(ws + 39845888);   // 16 MB: K (B,H,S,64)
  unsigned short* vt = (unsigned short*)(ws + 56623104);   // 16 MB: V^T (B,H,64,S)

  hipLaunchKernelGGL(cvt_x, dim3(4096), dim3(256), 0, stream, x, xb);
  hipLaunchKernelGGL(cvt_wt, dim3(32, 32, 3), dim3(256), 0, stream, Wq, Wk, Wv, wt);
  hipLaunchKernelGGL(qkv_gemm, dim3(64, 8, 3), dim3(256), 0, stream,
                     xb, wt, bq, bk, bv, qb, kb, vt);
  hipLaunchKernelGGL(attn, dim3(1024), dim3(256), 0, stream, qb, kb, vt, out);
}

// Round 5
// 224.779 us; speedup vs baseline: 2.9804x; 1.0140x over previous
//
#include <hip/hip_runtime.h>

typedef __bf16 bf16x8 __attribute__((ext_vector_type(8)));
typedef __bf16 bf16x4 __attribute__((ext_vector_type(4)));
typedef short s16x4 __attribute__((ext_vector_type(4)));
typedef float f32x4 __attribute__((ext_vector_type(4)));
typedef unsigned short u16x8 __attribute__((ext_vector_type(8)));
typedef unsigned short u16x4 __attribute__((ext_vector_type(4)));
typedef unsigned int u32x2 __attribute__((ext_vector_type(2)));
typedef unsigned int __attribute__((address_space(1))) as1_uint;
typedef unsigned int __attribute__((address_space(3))) as3_uint;

#define S_LEN 2048
#define NB 4
#define NH 16
#define HD 64
#define DM 1024

// 0.125 (1/sqrt(64)) * log2(e): Q is pre-scaled so attn does exp2 directly.
#define Q_SCALE 0.18033688011112042f

__device__ __forceinline__ unsigned short f2bf(float f) {
  union { float f; unsigned int u; } v; v.f = f;
  unsigned int r = v.u + 0x7fffu + ((v.u >> 16) & 1u);
  return (unsigned short)(r >> 16);
}

__device__ __forceinline__ unsigned int fbits(float f) {
  union { float f; unsigned int u; } v; v.f = f;
  return v.u;
}

// 16x16x16 bf16 MFMA with builtin-name portability.
__device__ __forceinline__ f32x4 mfma16(u16x4 a, u16x4 b, f32x4 c) {
#if __has_builtin(__builtin_amdgcn_mfma_f32_16x16x16_bf16)
  return __builtin_amdgcn_mfma_f32_16x16x16_bf16(
      __builtin_bit_cast(bf16x4, a), __builtin_bit_cast(bf16x4, b), c, 0, 0, 0);
#else
  return __builtin_amdgcn_mfma_f32_16x16x16bf16_1k(
      __builtin_bit_cast(s16x4, a), __builtin_bit_cast(s16x4, b), c, 0, 0, 0);
#endif
}

// ---------- kernel 1: X fp32 -> bf16 (layout preserved, 8192x1024) ----------
__global__ __launch_bounds__(256) void cvt_x(const float* __restrict__ x,
                                             unsigned short* __restrict__ xb) {
  int i = (blockIdx.x * 256 + threadIdx.x) * 8;
  f32x4 a = *(const f32x4*)(x + i);
  f32x4 b = *(const f32x4*)(x + i + 4);
  u16x8 o;
  o[0] = f2bf(a[0]); o[1] = f2bf(a[1]); o[2] = f2bf(a[2]); o[3] = f2bf(a[3]);
  o[4] = f2bf(b[0]); o[5] = f2bf(b[1]); o[6] = f2bf(b[2]); o[7] = f2bf(b[3]);
  *(u16x8*)(xb + i) = o;
}

// ---------- kernel 2: W (K,N) fp32 -> WT (N,K) bf16, for q/k/v via blockIdx.z ----------
__global__ __launch_bounds__(256) void cvt_wt(const float* __restrict__ Wq,
                                              const float* __restrict__ Wk,
                                              const float* __restrict__ Wv,
                                              unsigned short* __restrict__ wt) {
  const float* W = (blockIdx.z == 0) ? Wq : (blockIdx.z == 1) ? Wk : Wv;
  unsigned short* WT = wt + (size_t)blockIdx.z * DM * DM;
  __shared__ float tile[32][33];
  int tx = threadIdx.x & 31, ty = threadIdx.x >> 5;
  int k0 = blockIdx.x * 32, n0 = blockIdx.y * 32;
#pragma unroll
  for (int i = 0; i < 4; ++i)
    tile[ty + 8 * i][tx] = W[(size_t)(k0 + ty + 8 * i) * DM + n0 + tx];
  __syncthreads();
#pragma unroll
  for (int i = 0; i < 4; ++i)
    WT[(size_t)(n0 + ty + 8 * i) * DM + k0 + tx] = f2bf(tile[tx][ty + 8 * i]);
}

// ---------- kernel 3: QKV GEMM: Y = Xb @ W + b ----------
// z=0 -> Q*Q_SCALE (B,H,S,HD) bf16 ; z=1 -> K (B,H,S,HD) bf16 ; z=2 -> V^T (B,H,64,S) bf16
// LDS chunk XOR swizzle: logical chunk `q` of row r lives at physical chunk
// q ^ ((r>>1)&3), folded into the GLOBAL source address (stays within the
// row's 64B line -> coalescing unchanged). b128 fragment reads become 2-way
// bank-aliased (free) instead of 8-way.
__global__ __launch_bounds__(256) void qkv_gemm(const unsigned short* __restrict__ xb,
                                                const unsigned short* __restrict__ wt,
                                                const float* __restrict__ bq,
                                                const float* __restrict__ bk,
                                                const float* __restrict__ bv,
                                                unsigned short* __restrict__ qo,
                                                unsigned short* __restrict__ ko,
                                                unsigned short* __restrict__ vto) {
  const int z = blockIdx.z;
  const unsigned short* WT = wt + (size_t)z * DM * DM;
  const float* bias = (z == 0) ? bq : (z == 1) ? bk : bv;
  const int m0 = blockIdx.x * 128;
  const int n0 = blockIdx.y * 128;
  __shared__ __align__(16) unsigned short Al[128 * 32];
  __shared__ __align__(16) unsigned short Bl[128 * 32];
  const int tid = threadIdx.x;
  const int wave = tid >> 6, lane = tid & 63, quad = lane >> 4, lw = lane & 15;
  const int wm = (wave >> 1) * 64, wn = (wave & 1) * 64;

  f32x4 acc[4][4];
#pragma unroll
  for (int mt = 0; mt < 4; ++mt)
#pragma unroll
    for (int nt = 0; nt < 4; ++nt) acc[mt][nt] = (f32x4){0.f, 0.f, 0.f, 0.f};

  for (int k0 = 0; k0 < DM; k0 += 32) {
    __syncthreads();
#pragma unroll
    for (int i = 0; i < 2; ++i) {
      int c = i * 256 + tid;
      int row = c >> 2;
      int scn = (c & 3) ^ ((row >> 1) & 3);  // swizzled source chunk
      const unsigned short* ga = xb + (size_t)(m0 + row) * DM + k0 + scn * 8;
      __builtin_amdgcn_global_load_lds((const as1_uint*)ga, (as3_uint*)(Al + c * 8), 16, 0, 0);
      const unsigned short* gb = WT + (size_t)(n0 + row) * DM + k0 + scn * 8;
      __builtin_amdgcn_global_load_lds((const as1_uint*)gb, (as3_uint*)(Bl + c * 8), 16, 0, 0);
    }
    __syncthreads();
    bf16x8 af[4], bfr[4];
#pragma unroll
    for (int mt = 0; mt < 4; ++mt) {
      int r = wm + mt * 16 + lw;
      af[mt] = *(const bf16x8*)(Al + r * 32 + (quad ^ ((r >> 1) & 3)) * 8);
    }
#pragma unroll
    for (int nt = 0; nt < 4; ++nt) {
      int r = wn + nt * 16 + lw;
      bfr[nt] = *(const bf16x8*)(Bl + r * 32 + (quad ^ ((r >> 1) & 3)) * 8);
    }
#pragma unroll
    for (int mt = 0; mt < 4; ++mt)
#pragma unroll
      for (int nt = 0; nt < 4; ++nt)
        acc[mt][nt] = __builtin_amdgcn_mfma_f32_16x16x32_bf16(af[mt], bfr[nt], acc[mt][nt], 0, 0, 0);
  }

  float bias4[4];
#pragma unroll
  for (int nt = 0; nt < 4; ++nt) bias4[nt] = bias[n0 + wn + nt * 16 + lw];

  if (z < 2) {
    unsigned short* dst = (z == 0) ? qo : ko;
    const float sc = (z == 0) ? Q_SCALE : 1.0f;
#pragma unroll
    for (int mt = 0; mt < 4; ++mt) {
#pragma unroll
      for (int nt = 0; nt < 4; ++nt) {
        int n = n0 + wn + nt * 16 + lw;
        int h = n >> 6, d = n & 63;
#pragma unroll
        for (int r = 0; r < 4; ++r) {
          int m = m0 + wm + mt * 16 + quad * 4 + r;
          int b = m >> 11, s = m & 2047;
          dst[((size_t)(b * NH + h) * S_LEN + s) * HD + d] = f2bf((acc[mt][nt][r] + bias4[nt]) * sc);
        }
      }
    }
  } else {
#pragma unroll
    for (int mt = 0; mt < 4; ++mt) {
#pragma unroll
      for (int nt = 0; nt < 4; ++nt) {
        int n = n0 + wn + nt * 16 + lw;
        int h = n >> 6, d = n & 63;
        int mb = m0 + wm + mt * 16 + quad * 4;
        int b = mb >> 11, s = mb & 2047;
        u16x4 pk;
#pragma unroll
        for (int r = 0; r < 4; ++r) pk[r] = f2bf(acc[mt][nt][r] + bias4[nt]);
        *(u16x4*)(vto + ((size_t)(b * NH + h) * HD + d) * S_LEN + s) = pk;
      }
    }
  }
}

// ---------- kernel 4: causal flash attention, register-resident P ------------
// S^T = K·Q^T via mfma 16x16x32 (A=K, B=Q); S^T's C-layout IS the A-layout of
// mfma 16x16x16 so P feeds PV from registers. l = P@1. Double-buffered K/V
// staging: prefetch for tile t+1 is issued AFTER the barrier publishing tile t,
// so the compiler's vmcnt(0)-at-barrier drain happens a full compute-phase
// later. Complementary pairing: 33 rg-tile units per block; grid 1024 = fully
// resident; flat id swizzled for per-(b,h) XCD L2 locality.
__global__ __launch_bounds__(256, 4) void attn(const unsigned short* __restrict__ Qb,
                                               const unsigned short* __restrict__ Kb,
                                               const unsigned short* __restrict__ Vtb,
                                               float* __restrict__ out) {
  const int flat = blockIdx.x;
  const int bh_lo = flat & 7;
  const int qpair = (flat >> 3) & 15;
  const int bh_hi = flat >> 7;
  const int bh = bh_lo + 8 * bh_hi;
  const int b = bh >> 4, h = bh & 15;
  const int tid = threadIdx.x;
  const int wave = tid >> 6, lane = tid & 63;
  const int quad = lane >> 4, lw = lane & 15;
  const int qlo = qpair * 64;         // row group 0
  const int qhi = (31 - qpair) * 64;  // row group 1
  const unsigned short* Qp = Qb + (size_t)bh * S_LEN * HD;
  const unsigned short* Kp = Kb + (size_t)bh * S_LEN * HD;
  const unsigned short* Vp = Vtb + (size_t)bh * HD * S_LEN;

  __shared__ __align__(16) unsigned short Kl[2][64 * 64];
  __shared__ __align__(16) unsigned short Vl[2][64 * 64];

  // Q fragments (B-operand: n=qrow=lane&15, k=quad*8+j)
  bf16x8 aq[2][2];
#pragma unroll
  for (int rg = 0; rg < 2; ++rg) {
    const int qbase = rg ? qhi : qlo;
#pragma unroll
    for (int kc = 0; kc < 2; ++kc)
      aq[rg][kc] = *(const bf16x8*)(Qp + (size_t)(qbase + wave * 16 + lw) * HD + kc * 32 + quad * 8);
  }

  u16x4 ones4;
#pragma unroll
  for (int i = 0; i < 4; ++i) ones4[i] = 0x3F80;

  f32x4 accO[2][4];
  f32x4 accL[2];
#pragma unroll
  for (int rg = 0; rg < 2; ++rg) {
    accL[rg] = (f32x4){0.f, 0.f, 0.f, 0.f};
#pragma unroll
    for (int dg = 0; dg < 4; ++dg) accO[rg][dg] = (f32x4){0.f, 0.f, 0.f, 0.f};
  }

  const int qr0 = qlo + wave * 16 + lw;
  const int qr1 = qhi + wave * 16 + lw;

  const int T = 32 - qpair;

  // prologue: stage tile 0 into buffer 0
  {
#pragma unroll
    for (int i = 0; i < 2; ++i) {
      int idx = i * 256 + tid;
      int r = idx >> 3, c = (idx & 7) ^ (r & 7);
      __builtin_amdgcn_global_load_lds((const as1_uint*)(Kp + (size_t)r * HD + c * 8),
                                       (as3_uint*)(Kl[0] + idx * 8), 16, 0, 0);
      __builtin_amdgcn_global_load_lds((const as1_uint*)(Vp + (size_t)r * S_LEN + c * 8),
                                       (as3_uint*)(Vl[0] + idx * 8), 16, 0, 0);
    }
  }

  for (int t = 0; t < T; ++t) {
    const int kv = t * 64;
    const int cur = t & 1;
    __syncthreads();  // buf[cur] staged; all waves done reading buf[cur^1]

    if (t + 1 < T) {  // prefetch next tile; drains only at NEXT barrier
      const int kvn = kv + 64;
#pragma unroll
      for (int i = 0; i < 2; ++i) {
        int idx = i * 256 + tid;
        int r = idx >> 3, c = (idx & 7) ^ (r & 7);
        __builtin_amdgcn_global_load_lds((const as1_uint*)(Kp + (size_t)(kvn + r) * HD + c * 8),
                                         (as3_uint*)(Kl[cur ^ 1] + idx * 8), 16, 0, 0);
        __builtin_amdgcn_global_load_lds((const as1_uint*)(Vp + (size_t)r * S_LEN + kvn + c * 8),
                                         (as3_uint*)(Vl[cur ^ 1] + idx * 8), 16, 0, 0);
      }
    }

    const bool a0 = (t <= qpair);   // rg0 active this tile (wave-uniform)
    const bool d0 = (t == qpair);   // rg0 diagonal tile
    const bool d1 = (t == T - 1);   // rg1 diagonal tile

#pragma unroll
    for (int g = 0; g < 4; ++g) {
      const unsigned short* kp = Kl[cur] + (g * 16 + lw) * 64;
      const int sw = lw & 7;
      bf16x8 kf0 = *(const bf16x8*)(kp + ((quad ^ sw) * 8));
      bf16x8 kf1 = *(const bf16x8*)(kp + (((4 + quad) ^ sw) * 8));

      u16x4 pf[2];
#pragma unroll
      for (int rg = 0; rg < 2; ++rg) {
        if (rg == 0 && !a0) continue;
        f32x4 s = (f32x4){0.f, 0.f, 0.f, 0.f};
        s = __builtin_amdgcn_mfma_f32_16x16x32_bf16(kf0, aq[rg][0], s, 0, 0, 0);
        s = __builtin_amdgcn_mfma_f32_16x16x32_bf16(kf1, aq[rg][1], s, 0, 0, 0);
        const bool dg_ = rg ? d1 : d0;
        const int qr = rg ? qr1 : qr0;
        if (dg_) {
#pragma unroll
          for (int r = 0; r < 4; ++r) {
            float e = __builtin_amdgcn_exp2f(s[r]);
            s[r] = (kv + g * 16 + quad * 4 + r > qr) ? 0.f : e;
          }
        } else {
#pragma unroll
          for (int r = 0; r < 4; ++r) s[r] = __builtin_amdgcn_exp2f(s[r]);
        }
        u32x2 pk;
        pk[0] = (fbits(s[1]) & 0xFFFF0000u) | (fbits(s[0]) >> 16);
        pk[1] = (fbits(s[3]) & 0xFFFF0000u) | (fbits(s[2]) >> 16);
        pf[rg] = __builtin_bit_cast(u16x4, pk);
      }

#pragma unroll
      for (int dg = 0; dg < 4; ++dg) {
        const int row = dg * 16 + lw;
        const int slot = (2 * g + (quad >> 1)) ^ (lw & 7);
        u16x4 vf = *(const u16x4*)(Vl[cur] + row * 64 + slot * 8 + (quad & 1) * 4);
        if (a0) accO[0][dg] = mfma16(pf[0], vf, accO[0][dg]);
        accO[1][dg] = mfma16(pf[1], vf, accO[1][dg]);
      }
      if (a0) accL[0] = mfma16(pf[0], ones4, accL[0]);
      accL[1] = mfma16(pf[1], ones4, accL[1]);
    }
  }

#pragma unroll
  for (int rg = 0; rg < 2; ++rg) {
    const int qbase = rg ? qhi : qlo;
    float* op = out + ((size_t)b * S_LEN + qbase + wave * 16 + quad * 4) * DM + h * HD + lw;
#pragma unroll
    for (int r = 0; r < 4; ++r) {
      float inv = 1.0f / accL[rg][r];
#pragma unroll
      for (int dg = 0; dg < 4; ++dg) op[(size_t)r * DM + dg * 16] = accO[rg][dg][r] * inv;
    }
  }
}

extern "C" void kernel_launch(void* const* d_in, const int* in_sizes, int n_in,
                              void* d_out, int out_size, void* d_ws, size_t ws_size,
                              hipStream_t stream) {
  const float* x = (const float*)d_in[0];
  const float* Wq = (const float*)d_in[1];
  const float* bq = (const float*)d_in[2];
  const float* Wk = (const float*)d_in[3];
  const float* bk = (const float*)d_in[4];
  const float* Wv = (const float*)d_in[5];
  const float* bv = (const float*)d_in[6];
  float* out = (float*)d_out;

  char* ws = (char*)d_ws;
  unsigned short* xb = (unsigned short*)(ws + 0);          // 16 MB: X bf16 (8192,1024)
  unsigned short* wt = (unsigned short*)(ws + 16777216);   // 6 MB: Wq/Wk/Wv^T bf16
  unsigned short* qb = (unsigned short*)(ws + 23068672);   // 16 MB: Q*scale (B,H,S,64)
  unsigned short* kb = (unsigned short*)(ws + 39845888);   // 16 MB: K (B,H,S,64)
  unsigned short* vt = (unsigned short*)(ws + 56623104);   // 16 MB: V^T (B,H,64,S)

  hipLaunchKernelGGL(cvt_x, dim3(4096), dim3(256), 0, stream, x, xb);
  hipLaunchKernelGGL(cvt_wt, dim3(32, 32, 3), dim3(256), 0, stream, Wq, Wk, Wv, wt);
  hipLaunchKernelGGL(qkv_gemm, dim3(64, 8, 3), dim3(256), 0, stream,
                     xb, wt, bq, bk, bv, qb, kb, vt);
  hipLaunchKernelGGL(attn, dim3(1024), dim3(256), 0, stream, qb, kb, vt, out);
}